// Round 10
// baseline (17.498 us; speedup 1.0000x reference)
//
#include <hip/hip_runtime.h>

#define TJ 256
#define II 2
#define NGRP 8
#define DELTA 10.0f

// --- module globals: zero at load; finalizing block restores them to zero ---
// 8 groups x 8 quantities, each accumulator on its own 128-B line:
// block bid adds into group (bid & 7) -> per-line contention is nb/8 RMWs.
struct PaddedAcc { double v; double pad[15]; };
__device__ PaddedAcc g_acc[NGRP][8];   // zero-initialized at module load
__device__ unsigned g_ticket = 0;

// Single dispatch, no memset. Math identity:
//   loss = [Nn*A2 - 2*A1*S1 + P*S2 - corr] / (P*Nn),  T = tc / (P*Nn)
// A1=sum(10+x), A2=sum((10+x)^2) over positives; S1,S2 over negatives;
// corr = sum over clipped (pos,neg) pairs of min(10+x-y,0)^2 (normally 0);
// tc = #(pos,neg) pairs with x>y.
// Cross-block combine: relaxed device-scope atomicAdd (coherent across XCDs,
// no fences/acquire sweeps - R6 showed those cost ~40us). Block-local order
// (data adds before ticket add) via s_waitcnt vmcnt(0). Last ticket holder
// reads accumulators with add-zero RMWs, writes outputs, then atomicExch-
// resets the globals. No spinning; identical work every call.
__global__ void __launch_bounds__(256)
fused_kernel(const float* __restrict__ pred, const int* __restrict__ target,
             int B, int nTj, int nb, float* __restrict__ out) {
    __shared__ float vsh[TJ];     // compacted neg preds, pad=+1e30
    __shared__ float wsh[TJ];     // compacted neg preds, pad=-1e30
    __shared__ int   swtot[4];
    __shared__ float smaxs[4];
    __shared__ double sred[4][8];
    __shared__ double sfin[NGRP][8];
    __shared__ double fin[8];
    __shared__ unsigned s_last;

    const int tid = threadIdx.x;
    const int lane = tid & 63;
    const int wv = tid >> 6;
    const int bi = blockIdx.x / nTj;
    const int bj = blockIdx.x % nTj;

    // ---- stage + compact j tile; bi==0 blocks also fold the O(B) moments ----
    const int jg = bj * TJ + tid;
    float y = 0.0f; int t = -1;
    if (jg < B) { y = pred[jg]; t = target[jg]; }
    const bool isneg = (t == 0);

    double a1 = 0, a2 = 0, s1 = 0, s2 = 0, Pc = 0, Nc = 0;
    if (bi == 0) {  // j-tiles of bi==0 blocks partition [0,B)
        if (t == 1) { const double z = 10.0 + (double)y; a1 = z; a2 = z * z; Pc = 1.0; }
        else if (isneg) { const double yd = (double)y; s1 = yd; s2 = yd * yd; Nc = 1.0; }
    }

    const unsigned long long m = __ballot(isneg);
    const unsigned long long lm = (1ull << lane) - 1ull;
    const int ppre = __popcll(m & lm);
    if (lane == 0) swtot[wv] = __popcll(m);
    float wmax = isneg ? y : -1e30f;
    #pragma unroll
    for (int off = 32; off > 0; off >>= 1)
        wmax = fmaxf(wmax, __shfl_xor(wmax, off));
    if (lane == 0) smaxs[wv] = wmax;
    __syncthreads();

    int base = 0;
    #pragma unroll
    for (int w = 0; w < 4; ++w) base += (w < wv) ? swtot[w] : 0;
    const int nneg = swtot[0] + swtot[1] + swtot[2] + swtot[3];
    const int npad = (nneg + 3) & ~3;
    const float tileMax = fmaxf(fmaxf(smaxs[0], smaxs[1]),
                                fmaxf(smaxs[2], smaxs[3]));
    if (isneg) { vsh[base + ppre] = y; wsh[base + ppre] = y; }
    if (tid < npad - nneg) { vsh[nneg + tid] = 1e30f; wsh[nneg + tid] = -1e30f; }
    __syncthreads();

    // ---- II i-values per thread (register blocking: 1 LDS read -> 8 pairs) ----
    float u[II], xx[II];
    float xmin = 1e30f;
    #pragma unroll
    for (int k = 0; k < II; ++k) {
        u[k] = -1e30f; xx[k] = 1e30f;
        const int ig = bi * (II * 256) + k * 256 + tid;
        if (ig < B && target[ig] == 1) {
            const float x = pred[ig];
            u[k] = x; xx[k] = DELTA + x;
        }
        xmin = fminf(xmin, xx[k]);
    }

    unsigned tc = 0;
    float corr = 0.0f;
    const int nj4 = npad >> 2;
    const float4* v4 = (const float4*)vsh;
    if (__all(xmin >= tileMax)) {
        // fast path: no pair in this (wave, tile) can clip the hinge
        #pragma unroll 4
        for (int jj = 0; jj < nj4; ++jj) {
            const float4 vv = v4[jj];
            #pragma unroll
            for (int k = 0; k < II; ++k) {
                tc += (u[k] > vv.x);
                tc += (u[k] > vv.y);
                tc += (u[k] > vv.z);
                tc += (u[k] > vv.w);
            }
        }
    } else {
        const float4* w4 = (const float4*)wsh;
        #pragma unroll 2
        for (int jj = 0; jj < nj4; ++jj) {
            const float4 vv = v4[jj];
            const float4 ww = w4[jj];
            #pragma unroll
            for (int k = 0; k < II; ++k) {
                float dm;
                tc += (u[k] > vv.x); dm = fminf(xx[k] - ww.x, 0.0f); corr = fmaf(dm, dm, corr);
                tc += (u[k] > vv.y); dm = fminf(xx[k] - ww.y, 0.0f); corr = fmaf(dm, dm, corr);
                tc += (u[k] > vv.z); dm = fminf(xx[k] - ww.z, 0.0f); corr = fmaf(dm, dm, corr);
                tc += (u[k] > vv.w); dm = fminf(xx[k] - ww.w, 0.0f); corr = fmaf(dm, dm, corr);
            }
        }
    }

    // ---- block reduce 8 doubles (fixed order) ----
    double q[8] = {(double)tc, (double)corr, a1, a2, s1, s2, Pc, Nc};
    #pragma unroll
    for (int off = 32; off > 0; off >>= 1) {
        #pragma unroll
        for (int a = 0; a < 8; ++a) q[a] += __shfl_xor(q[a], off);
    }
    if (lane == 0) {
        #pragma unroll
        for (int a = 0; a < 8; ++a) sred[wv][a] = q[a];
    }
    __syncthreads();

    // ---- relaxed atomic accumulate into this block's group ----
    const int grp = blockIdx.x & (NGRP - 1);
    if (tid < 8) {
        const double tot = sred[0][tid] + sred[1][tid] + sred[2][tid] + sred[3][tid];
        atomicAdd(&g_acc[grp][tid].v, tot);
    }
    // this block's data adds must reach the coherent point before its ticket
    asm volatile("s_waitcnt vmcnt(0)" ::: "memory");
    if (tid == 0) {
        const unsigned old = atomicAdd(&g_ticket, 1u);
        s_last = (old == (unsigned)(nb - 1)) ? 1u : 0u;
    }
    __syncthreads();

    // ---- last block: read 8x8 (add-zero RMW, 64 parallel lines), emit, reset ----
    if (s_last) {
        if (tid < NGRP * 8)
            sfin[tid >> 3][tid & 7] = atomicAdd(&g_acc[tid >> 3][tid & 7].v, 0.0);
        __syncthreads();
        if (tid < 8) {
            double s = 0.0;
            #pragma unroll
            for (int g = 0; g < NGRP; ++g) s += sfin[g][tid];
            fin[tid] = s;
        }
        __syncthreads();
        if (tid == 0) {
            const double P = fin[6], Nn = fin[7];
            const double lossSum = Nn * fin[3] - 2.0 * fin[2] * fin[4]
                                 + P * fin[5] - fin[1];
            const double Np = P * Nn;
            out[0] = (float)(lossSum / Np);
            out[1] = (float)(fin[0] / Np);
        }
        // restore load-time state for the next call / graph replay
        if (tid < NGRP * 8) atomicExch(&g_acc[tid >> 3][tid & 7].v, 0.0);
        if (tid == 0) atomicExch(&g_ticket, 0u);
    }
}

extern "C" void kernel_launch(void* const* d_in, const int* in_sizes, int n_in,
                              void* d_out, int out_size, void* d_ws, size_t ws_size,
                              hipStream_t stream) {
    const float* pred = (const float*)d_in[0];
    const int* target = (const int*)d_in[1];
    const int B = in_sizes[0];

    const int nTi = (B + II * 256 - 1) / (II * 256);   // i-tiles of 512
    const int nTj = (B + TJ - 1) / TJ;                 // j-tiles of 256
    const int nb = nTi * nTj;                          // 16 * 32 = 512 for B=8192

    fused_kernel<<<nb, 256, 0, stream>>>(pred, target, B, nTj, nb, (float*)d_out);
}

// Round 11
// 17.368 us; speedup vs baseline: 1.0074x; 1.0074x over previous
//
#include <hip/hip_runtime.h>

#define TJ 256
#define II 8
#define NGRP 8
#define DELTA 10.0f

// --- module globals: zero at load; finalizing block restores them to zero ---
// 8 groups x 8 quantities, each accumulator on its own 128-B line:
// block bid adds into group (bid & 7) -> per-line contention is nb/8 RMWs.
struct PaddedAcc { double v; double pad[15]; };
__device__ PaddedAcc g_acc[NGRP][8];   // zero-initialized at module load
__device__ unsigned g_ticket = 0;

// Single dispatch, no memset. Math identity:
//   loss = [Nn*A2 - 2*A1*S1 + P*S2 - corr] / (P*Nn),  T = tc / (P*Nn)
// A1=sum(10+x), A2=sum((10+x)^2) over positives; S1,S2 over negatives;
// corr = sum over clipped (pos,neg) pairs of min(10+x-y,0)^2 (normally 0);
// tc = #(pos,neg) pairs with x>y.
// Cross-block combine: relaxed device-scope atomicAdd (coherent across XCDs,
// no fences/acquire sweeps - R6 showed those cost ~40us). Block-local order
// (data adds before ticket add) via s_waitcnt vmcnt(0). Last ticket holder
// reads accumulators with add-zero RMWs, writes outputs, then atomicExch-
// resets the globals. No spinning; identical work every call.
__global__ void __launch_bounds__(256)
fused_kernel(const float* __restrict__ pred, const int* __restrict__ target,
             int B, int nTj, int nb, float* __restrict__ out) {
    __shared__ float vsh[TJ];     // compacted neg preds, pad=+1e30
    __shared__ float wsh[TJ];     // compacted neg preds, pad=-1e30
    __shared__ int   swtot[4];
    __shared__ float smaxs[4];
    __shared__ double sred[4][8];
    __shared__ double sfin[NGRP][8];
    __shared__ double fin[8];
    __shared__ unsigned s_last;

    const int tid = threadIdx.x;
    const int lane = tid & 63;
    const int wv = tid >> 6;
    const int bi = blockIdx.x / nTj;
    const int bj = blockIdx.x % nTj;

    // ---- issue i-row loads EARLY so their latency hides under staging ----
    float yi[II]; int ti[II];
    #pragma unroll
    for (int k = 0; k < II; ++k) {
        const int ig = bi * (II * 256) + k * 256 + tid;
        yi[k] = 0.0f; ti[k] = -1;
        if (ig < B) { yi[k] = pred[ig]; ti[k] = target[ig]; }
    }

    // ---- stage + compact j tile; bi==0 blocks also fold the O(B) moments ----
    const int jg = bj * TJ + tid;
    float y = 0.0f; int t = -1;
    if (jg < B) { y = pred[jg]; t = target[jg]; }
    const bool isneg = (t == 0);

    double a1 = 0, a2 = 0, s1 = 0, s2 = 0, Pc = 0, Nc = 0;
    if (bi == 0) {  // j-tiles of bi==0 blocks partition [0,B)  (nTj*TJ >= B)
        if (t == 1) { const double z = 10.0 + (double)y; a1 = z; a2 = z * z; Pc = 1.0; }
        else if (isneg) { const double yd = (double)y; s1 = yd; s2 = yd * yd; Nc = 1.0; }
    }

    const unsigned long long m = __ballot(isneg);
    const unsigned long long lm = (1ull << lane) - 1ull;
    const int ppre = __popcll(m & lm);
    if (lane == 0) swtot[wv] = __popcll(m);
    float wmax = isneg ? y : -1e30f;
    #pragma unroll
    for (int off = 32; off > 0; off >>= 1)
        wmax = fmaxf(wmax, __shfl_xor(wmax, off));
    if (lane == 0) smaxs[wv] = wmax;
    __syncthreads();

    int base = 0;
    #pragma unroll
    for (int w = 0; w < 4; ++w) base += (w < wv) ? swtot[w] : 0;
    const int nneg = swtot[0] + swtot[1] + swtot[2] + swtot[3];
    const int npad = (nneg + 3) & ~3;
    const float tileMax = fmaxf(fmaxf(smaxs[0], smaxs[1]),
                                fmaxf(smaxs[2], smaxs[3]));
    if (isneg) { vsh[base + ppre] = y; wsh[base + ppre] = y; }
    if (tid < npad - nneg) { vsh[nneg + tid] = 1e30f; wsh[nneg + tid] = -1e30f; }
    __syncthreads();

    // ---- II i-values per thread (register blocking: 1 LDS read -> 32 pairs) ----
    float u[II], xx[II];
    float xmin = 1e30f;
    #pragma unroll
    for (int k = 0; k < II; ++k) {
        const bool isp = (ti[k] == 1);
        u[k]  = isp ? yi[k] : -1e30f;
        xx[k] = isp ? (DELTA + yi[k]) : 1e30f;
        xmin = fminf(xmin, xx[k]);
    }

    unsigned tc = 0;
    float corr = 0.0f;
    const int nj4 = npad >> 2;
    const float4* v4 = (const float4*)vsh;
    if (__all(xmin >= tileMax)) {
        // fast path: no pair in this (wave, tile) can clip the hinge
        #pragma unroll 4
        for (int jj = 0; jj < nj4; ++jj) {
            const float4 vv = v4[jj];
            #pragma unroll
            for (int k = 0; k < II; ++k) {
                tc += (u[k] > vv.x);
                tc += (u[k] > vv.y);
                tc += (u[k] > vv.z);
                tc += (u[k] > vv.w);
            }
        }
    } else {
        const float4* w4 = (const float4*)wsh;
        #pragma unroll 2
        for (int jj = 0; jj < nj4; ++jj) {
            const float4 vv = v4[jj];
            const float4 ww = w4[jj];
            #pragma unroll
            for (int k = 0; k < II; ++k) {
                float dm;
                tc += (u[k] > vv.x); dm = fminf(xx[k] - ww.x, 0.0f); corr = fmaf(dm, dm, corr);
                tc += (u[k] > vv.y); dm = fminf(xx[k] - ww.y, 0.0f); corr = fmaf(dm, dm, corr);
                tc += (u[k] > vv.z); dm = fminf(xx[k] - ww.z, 0.0f); corr = fmaf(dm, dm, corr);
                tc += (u[k] > vv.w); dm = fminf(xx[k] - ww.w, 0.0f); corr = fmaf(dm, dm, corr);
            }
        }
    }

    // ---- block reduce 8 doubles (fixed order) ----
    double q[8] = {(double)tc, (double)corr, a1, a2, s1, s2, Pc, Nc};
    #pragma unroll
    for (int off = 32; off > 0; off >>= 1) {
        #pragma unroll
        for (int a = 0; a < 8; ++a) q[a] += __shfl_xor(q[a], off);
    }
    if (lane == 0) {
        #pragma unroll
        for (int a = 0; a < 8; ++a) sred[wv][a] = q[a];
    }
    __syncthreads();

    // ---- relaxed atomic accumulate into this block's group ----
    const int grp = blockIdx.x & (NGRP - 1);
    if (tid < 8) {
        const double tot = sred[0][tid] + sred[1][tid] + sred[2][tid] + sred[3][tid];
        atomicAdd(&g_acc[grp][tid].v, tot);
    }
    // this block's data adds must reach the coherent point before its ticket
    asm volatile("s_waitcnt vmcnt(0)" ::: "memory");
    if (tid == 0) {
        const unsigned old = atomicAdd(&g_ticket, 1u);
        s_last = (old == (unsigned)(nb - 1)) ? 1u : 0u;
    }
    __syncthreads();

    // ---- last block: read 8x8 (add-zero RMW, 64 parallel lines), emit, reset ----
    if (s_last) {
        if (tid < NGRP * 8)
            sfin[tid >> 3][tid & 7] = atomicAdd(&g_acc[tid >> 3][tid & 7].v, 0.0);
        __syncthreads();
        if (tid < 8) {
            double s = 0.0;
            #pragma unroll
            for (int g = 0; g < NGRP; ++g) s += sfin[g][tid];
            fin[tid] = s;
        }
        __syncthreads();
        if (tid == 0) {
            const double P = fin[6], Nn = fin[7];
            const double lossSum = Nn * fin[3] - 2.0 * fin[2] * fin[4]
                                 + P * fin[5] - fin[1];
            const double Np = P * Nn;
            out[0] = (float)(lossSum / Np);
            out[1] = (float)(fin[0] / Np);
        }
        // restore load-time state for the next call / graph replay
        if (tid < NGRP * 8) atomicExch(&g_acc[tid >> 3][tid & 7].v, 0.0);
        if (tid == 0) atomicExch(&g_ticket, 0u);
    }
}

extern "C" void kernel_launch(void* const* d_in, const int* in_sizes, int n_in,
                              void* d_out, int out_size, void* d_ws, size_t ws_size,
                              hipStream_t stream) {
    const float* pred = (const float*)d_in[0];
    const int* target = (const int*)d_in[1];
    const int B = in_sizes[0];

    const int nTi = (B + II * 256 - 1) / (II * 256);   // i-tiles of 2048
    const int nTj = (B + TJ - 1) / TJ;                 // j-tiles of 256
    const int nb = nTi * nTj;                          // 4 * 32 = 128 for B=8192

    fused_kernel<<<nb, 256, 0, stream>>>(pred, target, B, nTj, nb, (float*)d_out);
}

// Round 12
// 15.415 us; speedup vs baseline: 1.1351x; 1.1267x over previous
//
#include <hip/hip_runtime.h>

#define TJ 256
#define II 4
#define NGRP 8
#define DELTA 10.0f

// --- module globals: zero at load; finalizing block restores them to zero ---
// 8 groups x 8 quantities, each accumulator on its own 128-B line:
// block bid adds into group (bid & 7) -> per-line contention is nb/8 RMWs.
struct PaddedAcc { double v; double pad[15]; };
__device__ PaddedAcc g_acc[NGRP][8];   // zero-initialized at module load
__device__ unsigned g_ticket = 0;

// Single dispatch, no memset. Math identity:
//   loss = [Nn*A2 - 2*A1*S1 + P*S2 - corr] / (P*Nn),  T = tc / (P*Nn)
// A1=sum(10+x), A2=sum((10+x)^2) over positives; S1,S2 over negatives;
// corr = sum over clipped (pos,neg) pairs of min(10+x-y,0)^2 (normally 0);
// tc = #(pos,neg) pairs with x>y.
// Cross-block combine: relaxed device-scope atomicAdd (coherent across XCDs,
// no fences/acquire sweeps - R6 showed those cost ~40us). Block-local order
// (data adds before ticket add) via s_waitcnt vmcnt(0). Last ticket holder
// reads accumulators with add-zero RMWs, writes outputs, then atomicExch-
// resets the globals. No spinning; identical work every call.
// Block count: 256 (1/CU) measured optimal (R10:512=17.5, R9:256=16.7,
// R11:128=17.4).
__global__ void __launch_bounds__(256)
fused_kernel(const float* __restrict__ pred, const int* __restrict__ target,
             int B, int nTj, int nb, float* __restrict__ out) {
    __shared__ float vsh[TJ];     // compacted neg preds, pad=+1e30
    __shared__ float wsh[TJ];     // compacted neg preds, pad=-1e30
    __shared__ int   swtot[4];
    __shared__ float smaxs[4];
    __shared__ double sred[4][8];
    __shared__ double sfin[NGRP][8];
    __shared__ double fin[8];
    __shared__ unsigned s_last;

    const int tid = threadIdx.x;
    const int lane = tid & 63;
    const int wv = tid >> 6;
    const int bi = blockIdx.x / nTj;
    const int bj = blockIdx.x % nTj;

    // ---- issue i-row loads EARLY so their latency hides under staging ----
    float yi[II]; int ti[II];
    #pragma unroll
    for (int k = 0; k < II; ++k) {
        const int ig = bi * (II * 256) + k * 256 + tid;
        yi[k] = 0.0f; ti[k] = -1;
        if (ig < B) { yi[k] = pred[ig]; ti[k] = target[ig]; }
    }

    // ---- stage + compact j tile; bi==0 blocks also fold the O(B) moments ----
    const int jg = bj * TJ + tid;
    float y = 0.0f; int t = -1;
    if (jg < B) { y = pred[jg]; t = target[jg]; }
    const bool isneg = (t == 0);

    double a1 = 0, a2 = 0, s1 = 0, s2 = 0, Pc = 0, Nc = 0;
    if (bi == 0) {  // j-tiles of bi==0 blocks partition [0,B)  (nTj*TJ >= B)
        if (t == 1) { const double z = 10.0 + (double)y; a1 = z; a2 = z * z; Pc = 1.0; }
        else if (isneg) { const double yd = (double)y; s1 = yd; s2 = yd * yd; Nc = 1.0; }
    }

    const unsigned long long m = __ballot(isneg);
    const unsigned long long lm = (1ull << lane) - 1ull;
    const int ppre = __popcll(m & lm);
    if (lane == 0) swtot[wv] = __popcll(m);
    float wmax = isneg ? y : -1e30f;
    #pragma unroll
    for (int off = 32; off > 0; off >>= 1)
        wmax = fmaxf(wmax, __shfl_xor(wmax, off));
    if (lane == 0) smaxs[wv] = wmax;
    __syncthreads();

    int base = 0;
    #pragma unroll
    for (int w = 0; w < 4; ++w) base += (w < wv) ? swtot[w] : 0;
    const int nneg = swtot[0] + swtot[1] + swtot[2] + swtot[3];
    const int npad = (nneg + 3) & ~3;
    const float tileMax = fmaxf(fmaxf(smaxs[0], smaxs[1]),
                                fmaxf(smaxs[2], smaxs[3]));
    if (isneg) { vsh[base + ppre] = y; wsh[base + ppre] = y; }
    if (tid < npad - nneg) { vsh[nneg + tid] = 1e30f; wsh[nneg + tid] = -1e30f; }
    __syncthreads();

    // ---- II i-values per thread (register blocking: 1 LDS read -> 16 pairs) ----
    float u[II], xx[II];
    float xmin = 1e30f;
    #pragma unroll
    for (int k = 0; k < II; ++k) {
        const bool isp = (ti[k] == 1);
        u[k]  = isp ? yi[k] : -1e30f;
        xx[k] = isp ? (DELTA + yi[k]) : 1e30f;
        xmin = fminf(xmin, xx[k]);
    }

    unsigned tc = 0;
    float corr = 0.0f;
    const int nj4 = npad >> 2;
    const float4* v4 = (const float4*)vsh;
    if (__all(xmin >= tileMax)) {
        // fast path: no pair in this (wave, tile) can clip the hinge
        #pragma unroll 4
        for (int jj = 0; jj < nj4; ++jj) {
            const float4 vv = v4[jj];
            #pragma unroll
            for (int k = 0; k < II; ++k) {
                tc += (u[k] > vv.x);
                tc += (u[k] > vv.y);
                tc += (u[k] > vv.z);
                tc += (u[k] > vv.w);
            }
        }
    } else {
        const float4* w4 = (const float4*)wsh;
        #pragma unroll 2
        for (int jj = 0; jj < nj4; ++jj) {
            const float4 vv = v4[jj];
            const float4 ww = w4[jj];
            #pragma unroll
            for (int k = 0; k < II; ++k) {
                float dm;
                tc += (u[k] > vv.x); dm = fminf(xx[k] - ww.x, 0.0f); corr = fmaf(dm, dm, corr);
                tc += (u[k] > vv.y); dm = fminf(xx[k] - ww.y, 0.0f); corr = fmaf(dm, dm, corr);
                tc += (u[k] > vv.z); dm = fminf(xx[k] - ww.z, 0.0f); corr = fmaf(dm, dm, corr);
                tc += (u[k] > vv.w); dm = fminf(xx[k] - ww.w, 0.0f); corr = fmaf(dm, dm, corr);
            }
        }
    }

    // ---- block reduce 8 doubles (fixed order) ----
    double q[8] = {(double)tc, (double)corr, a1, a2, s1, s2, Pc, Nc};
    #pragma unroll
    for (int off = 32; off > 0; off >>= 1) {
        #pragma unroll
        for (int a = 0; a < 8; ++a) q[a] += __shfl_xor(q[a], off);
    }
    if (lane == 0) {
        #pragma unroll
        for (int a = 0; a < 8; ++a) sred[wv][a] = q[a];
    }
    __syncthreads();

    // ---- relaxed atomic accumulate into this block's group ----
    const int grp = blockIdx.x & (NGRP - 1);
    if (tid < 8) {
        const double tot = sred[0][tid] + sred[1][tid] + sred[2][tid] + sred[3][tid];
        atomicAdd(&g_acc[grp][tid].v, tot);
    }
    // this block's data adds must reach the coherent point before its ticket
    asm volatile("s_waitcnt vmcnt(0)" ::: "memory");
    if (tid == 0) {
        const unsigned old = atomicAdd(&g_ticket, 1u);
        s_last = (old == (unsigned)(nb - 1)) ? 1u : 0u;
    }
    __syncthreads();

    // ---- last block: read 8x8 (add-zero RMW, 64 parallel lines), emit, reset ----
    if (s_last) {
        if (tid < NGRP * 8)
            sfin[tid >> 3][tid & 7] = atomicAdd(&g_acc[tid >> 3][tid & 7].v, 0.0);
        __syncthreads();
        if (tid < 8) {
            double s = 0.0;
            #pragma unroll
            for (int g = 0; g < NGRP; ++g) s += sfin[g][tid];
            fin[tid] = s;
        }
        __syncthreads();
        if (tid == 0) {
            const double P = fin[6], Nn = fin[7];
            const double lossSum = Nn * fin[3] - 2.0 * fin[2] * fin[4]
                                 + P * fin[5] - fin[1];
            const double Np = P * Nn;
            out[0] = (float)(lossSum / Np);
            out[1] = (float)(fin[0] / Np);
        }
        // restore load-time state for the next call / graph replay
        if (tid < NGRP * 8) atomicExch(&g_acc[tid >> 3][tid & 7].v, 0.0);
        if (tid == 0) atomicExch(&g_ticket, 0u);
    }
}

extern "C" void kernel_launch(void* const* d_in, const int* in_sizes, int n_in,
                              void* d_out, int out_size, void* d_ws, size_t ws_size,
                              hipStream_t stream) {
    const float* pred = (const float*)d_in[0];
    const int* target = (const int*)d_in[1];
    const int B = in_sizes[0];

    const int nTi = (B + II * 256 - 1) / (II * 256);   // i-tiles of 1024
    const int nTj = (B + TJ - 1) / TJ;                 // j-tiles of 256
    const int nb = nTi * nTj;                          // 8 * 32 = 256 for B=8192

    fused_kernel<<<nb, 256, 0, stream>>>(pred, target, B, nTj, nb, (float*)d_out);
}